// Round 6
// baseline (411.970 us; speedup 1.0000x reference)
//
#include <hip/hip_runtime.h>

#define S_LEN 512
#define H_DIM 128
#define C_DIM 10

typedef __attribute__((ext_vector_type(8))) short short8;
typedef __attribute__((ext_vector_type(4))) float f32x4;

__device__ __forceinline__ unsigned short f2bf(float f) {
    union { float f; unsigned u; } v; v.f = f;
    return (unsigned short)((v.u + 0x7FFFu + ((v.u >> 16) & 1u)) >> 16);
}

__device__ __forceinline__ float fast_sigmoid(float x) {
    float e = __builtin_amdgcn_exp2f(-1.4426950408889634f * x);
    return __builtin_amdgcn_rcpf(1.0f + e);
}
__device__ __forceinline__ float fast_tanh(float x) {
    float e = __builtin_amdgcn_exp2f(2.8853900817779268f * x);  // e^{2x}
    return 1.0f - 2.0f * __builtin_amdgcn_rcpf(e + 1.0f);
}

// R6: dual-stream latency hiding. 128 blocks x 512 threads (8 waves).
// Each block runs TWO independent 4-row batch groups (G0: rows b0..b0+3,
// G1: rows b0+4..b0+7) through all 512 steps, interleaved in one loop with
// ONE barrier per iteration (2 LSTM steps). G0's serial chain (ds_read ->
// MFMA -> activations -> ds_write) hides under G1's independent issue and
// vice versa. Both groups share the in-register Wh B-fragments.
// Per-group distribution = R2 optimum: wave w owns cols [16w,16w+16) of all
// 4 gates, batch row r at MFMA M-row 4r, 1 cell/lane/group.
// h in LDS in A-fragment order (conflict-free, R3/R5-verified 45K).
__global__ __launch_bounds__(512, 2) void lstm_fused(
    const float* __restrict__ x,
    const float* __restrict__ Wgx, const float* __restrict__ Wgh,
    const float* __restrict__ Wix, const float* __restrict__ Wih,
    const float* __restrict__ Wfx, const float* __restrict__ Wfh,
    const float* __restrict__ Wox, const float* __restrict__ Woh,
    const float* __restrict__ Wph,
    const float* __restrict__ bg, const float* __restrict__ bi,
    const float* __restrict__ bff, const float* __restrict__ bo,
    const float* __restrict__ bp,
    float* __restrict__ out)
{
    __shared__ float xr[8][516];                                          // x transposed, padded
    __shared__ __attribute__((aligned(16))) unsigned short hb[2][2][512]; // [group][parity], A-frag order
    __shared__ float hfin[8][H_DIM];

    const int tid  = threadIdx.x;
    const int lane = tid & 63;
    const int w    = tid >> 6;        // wave 0..7
    const int b0   = blockIdx.x * 8;  // batch row base (8 rows/block)

    // ---- stage x transposed (coalesced) ----
    {
        const float* xp = x + b0 * S_LEN;
        #pragma unroll
        for (int r = 0; r < 8; ++r) xr[r][tid] = xp[r * S_LEN + tid];
    }
    // zero all h buffers (1024 dwords)
    ((unsigned*)hb)[tid]       = 0;
    ((unsigned*)hb)[tid + 512] = 0;

    const int jl = lane & 15;
    const int kg = lane >> 4;         // 0..3 (batch row within group)
    const int j  = w * 16 + jl;       // owned h-col

    // ---- Wh into registers as B-fragments (bf16), shared by both groups ----
    // B-frag lane l elem e: k = 32*kk + 8*(l>>4) + e, n = l&15
    const float* WhA[4] = { Wgh, Wih, Wfh, Woh };
    short8 bfrag[4][4];
    #pragma unroll
    for (int g = 0; g < 4; ++g) {
        #pragma unroll
        for (int kk = 0; kk < 4; ++kk) {
            const float* src = WhA[g] + (kk * 32 + kg * 8) * H_DIM + j;
            short8 v;
            #pragma unroll
            for (int e = 0; e < 8; ++e) v[e] = (short)f2bf(src[e * H_DIM]);
            bfrag[g][kk] = v;
        }
    }
    const float wxv[4] = { Wgx[j], Wix[j], Wfx[j], Wox[j] };
    const float bv[4]  = { bg[j],  bi[j],  bff[j], bo[j]  };

    // A-frag read: active lanes lane%4==0 (q=lane/4) read bytes q*16 + kk*256
    const bool aActive = (lane & 3) == 0;
    const int  abase   = (lane >> 2) * 16;
    // h-write (batch kg, col j), ushort index in A-frag order
    const int  widx    = kg * 8 + ((j >> 3) & 3) * 32 + (j >> 5) * 128 + (j & 7);

    float cst0 = 0.f, cst1 = 0.f;
    float hcv0 = 0.f, hcv1 = 0.f;

    short8 af0[4], af1[4];
    #pragma unroll
    for (int kk = 0; kk < 4; ++kk) {
        af0[kk] = short8{0,0,0,0,0,0,0,0};
        af1[kk] = short8{0,0,0,0,0,0,0,0};
    }

    __syncthreads();

    unsigned short* const g0a = &hb[0][0][0];
    unsigned short* const g0b = &hb[0][1][0];
    unsigned short* const g1a = &hb[1][0][0];
    unsigned short* const g1b = &hb[1][1][0];

    auto iter = [&](const unsigned short* s0, unsigned short* d0,
                    const unsigned short* s1, unsigned short* d1,
                    float xv0, float xv1) {
        // both groups' A-fragment reads issue back-to-back (independent)
        if (aActive) {
            const char* base0 = (const char*)s0 + abase;
            const char* base1 = (const char*)s1 + abase;
            #pragma unroll
            for (int kk = 0; kk < 4; ++kk) {
                af0[kk] = *(const short8*)(base0 + kk * 256);
                af1[kk] = *(const short8*)(base1 + kk * 256);
            }
        }
        // off-chain seeds
        float seed0[4], seed1[4];
        #pragma unroll
        for (int g = 0; g < 4; ++g) {
            seed0[g] = __builtin_fmaf(xv0, wxv[g], bv[g]);
            seed1[g] = __builtin_fmaf(xv1, wxv[g], bv[g]);
        }

        const f32x4 zf = { 0.f, 0.f, 0.f, 0.f };
        f32x4 a00[4], a01[4], a10[4], a11[4];
        #pragma unroll
        for (int g = 0; g < 4; ++g) {
            a00[g] = __builtin_amdgcn_mfma_f32_16x16x32_bf16(af0[0], bfrag[g][0], zf, 0, 0, 0);
            a01[g] = __builtin_amdgcn_mfma_f32_16x16x32_bf16(af0[2], bfrag[g][2], zf, 0, 0, 0);
            a10[g] = __builtin_amdgcn_mfma_f32_16x16x32_bf16(af1[0], bfrag[g][0], zf, 0, 0, 0);
            a11[g] = __builtin_amdgcn_mfma_f32_16x16x32_bf16(af1[2], bfrag[g][2], zf, 0, 0, 0);
        }
        #pragma unroll
        for (int g = 0; g < 4; ++g) {
            a00[g] = __builtin_amdgcn_mfma_f32_16x16x32_bf16(af0[1], bfrag[g][1], a00[g], 0, 0, 0);
            a01[g] = __builtin_amdgcn_mfma_f32_16x16x32_bf16(af0[3], bfrag[g][3], a01[g], 0, 0, 0);
            a10[g] = __builtin_amdgcn_mfma_f32_16x16x32_bf16(af1[1], bfrag[g][1], a10[g], 0, 0, 0);
            a11[g] = __builtin_amdgcn_mfma_f32_16x16x32_bf16(af1[3], bfrag[g][3], a11[g], 0, 0, 0);
        }

        // G0 activations + write
        {
            float pre[4];
            #pragma unroll
            for (int g = 0; g < 4; ++g) pre[g] = a00[g][0] + (a01[g][0] + seed0[g]);
            const float tg = fast_tanh(pre[0]);
            const float si = fast_sigmoid(pre[1]);
            const float sf = fast_sigmoid(pre[2]);
            const float so = fast_sigmoid(pre[3]);
            const float cn = __builtin_fmaf(cst0, sf, tg * si);
            cst0 = cn;
            const float hn = fast_tanh(cn) * so;
            hcv0 = hn;
            unsigned pk;
            asm("v_cvt_pk_bf16_f32 %0, %1, %2" : "=v"(pk) : "v"(hn), "v"(hn));
            d0[widx] = (unsigned short)pk;
        }
        // G1 activations + write
        {
            float pre[4];
            #pragma unroll
            for (int g = 0; g < 4; ++g) pre[g] = a10[g][0] + (a11[g][0] + seed1[g]);
            const float tg = fast_tanh(pre[0]);
            const float si = fast_sigmoid(pre[1]);
            const float sf = fast_sigmoid(pre[2]);
            const float so = fast_sigmoid(pre[3]);
            const float cn = __builtin_fmaf(cst1, sf, tg * si);
            cst1 = cn;
            const float hn = fast_tanh(cn) * so;
            hcv1 = hn;
            unsigned pk;
            asm("v_cvt_pk_bf16_f32 %0, %1, %2" : "=v"(pk) : "v"(hn), "v"(hn));
            d1[widx] = (unsigned short)pk;
        }
        __syncthreads();   // one barrier for both steps
    };

    for (int t4 = 0; t4 < S_LEN; t4 += 4) {
        const f32x4 xq0 = *(const f32x4*)&xr[kg][t4];
        const f32x4 xq1 = *(const f32x4*)&xr[4 + kg][t4];
        iter(g0a, g0b, g1a, g1b, xq0[0], xq1[0]);
        iter(g0b, g0a, g1b, g1a, xq0[1], xq1[1]);
        iter(g0a, g0b, g1a, g1b, xq0[2], xq1[2]);
        iter(g0b, g0a, g1b, g1a, xq0[3], xq1[3]);
    }

    // ---- epilogue: logits = h_last @ W_ph + b_p ----
    hfin[kg][j]     = hcv0;
    hfin[4 + kg][j] = hcv1;
    __syncthreads();

    if (tid < 8 * C_DIM) {
        const int b = tid / C_DIM, cc = tid % C_DIM;
        float s = bp[cc];
        #pragma unroll 8
        for (int k = 0; k < H_DIM; ++k) s += hfin[b][k] * Wph[k * C_DIM + cc];
        out[(b0 + b) * C_DIM + cc] = s;
    }
}

extern "C" void kernel_launch(void* const* d_in, const int* in_sizes, int n_in,
                              void* d_out, int out_size, void* d_ws, size_t ws_size,
                              hipStream_t stream) {
    const float* x   = (const float*)d_in[0];
    const float* Wgx = (const float*)d_in[1];
    const float* Wgh = (const float*)d_in[2];
    const float* Wix = (const float*)d_in[3];
    const float* Wih = (const float*)d_in[4];
    const float* Wfx = (const float*)d_in[5];
    const float* Wfh = (const float*)d_in[6];
    const float* Wox = (const float*)d_in[7];
    const float* Woh = (const float*)d_in[8];
    const float* Wph = (const float*)d_in[9];
    const float* bg  = (const float*)d_in[10];
    const float* bi  = (const float*)d_in[11];
    const float* bf  = (const float*)d_in[12];
    const float* bo  = (const float*)d_in[13];
    const float* bp  = (const float*)d_in[14];
    float* out = (float*)d_out;

    lstm_fused<<<dim3(128), dim3(512), 0, stream>>>(
        x, Wgx, Wgh, Wix, Wih, Wfx, Wfh, Wox, Woh, Wph,
        bg, bi, bf, bo, bp, out);
}

// Round 7
// 246.520 us; speedup vs baseline: 1.6711x; 1.6711x over previous
//
#include <hip/hip_runtime.h>

#define S_LEN 512
#define H_DIM 128
#define C_DIM 10

typedef __attribute__((ext_vector_type(8))) short short8;
typedef __attribute__((ext_vector_type(4))) float f32x4;

__device__ __forceinline__ unsigned short f2bf(float f) {
    union { float f; unsigned u; } v; v.f = f;
    return (unsigned short)((v.u + 0x7FFFu + ((v.u >> 16) & 1u)) >> 16);
}

__device__ __forceinline__ float fast_sigmoid(float x) {
    float e = __builtin_amdgcn_exp2f(-1.4426950408889634f * x);
    return __builtin_amdgcn_rcpf(1.0f + e);
}
__device__ __forceinline__ float fast_tanh(float x) {
    float e = __builtin_amdgcn_exp2f(2.8853900817779268f * x);  // e^{2x}
    return 1.0f - 2.0f * __builtin_amdgcn_rcpf(e + 1.0f);
}

// R7 = R2 skeleton (best measured: 218us) + chain shavings.
// 256 blocks x 512 threads (8 waves), 4 batch rows/block at MFMA M-rows 4b,
// wave w owns cols [16w,16w+16) of all 4 gates (16 MFMA/wave/step, 1 LSTM
// cell per lane). h in LDS in A-fragment order (conflict-free, 45K).
// Shavings: (1) x-proj+bias seeded into MFMA C operand (splat, off-chain)
// - removes the post-MFMA add tree; (2) s_setprio(1) across the serial
// activation+write tail - laggard wave gets priority, less barrier skew;
// (3) x quad prefetched one iteration ahead - off the post-barrier burst.
__global__ __launch_bounds__(512, 2) void lstm_fused(
    const float* __restrict__ x,
    const float* __restrict__ Wgx, const float* __restrict__ Wgh,
    const float* __restrict__ Wix, const float* __restrict__ Wih,
    const float* __restrict__ Wfx, const float* __restrict__ Wfh,
    const float* __restrict__ Wox, const float* __restrict__ Woh,
    const float* __restrict__ Wph,
    const float* __restrict__ bg, const float* __restrict__ bi,
    const float* __restrict__ bff, const float* __restrict__ bo,
    const float* __restrict__ bp,
    float* __restrict__ out)
{
    __shared__ float xr[4][516];                                       // x transposed, padded
    __shared__ __attribute__((aligned(16))) unsigned short hb[2][512]; // h bf16, A-frag order
    __shared__ float hfin[4][H_DIM];

    const int tid  = threadIdx.x;
    const int lane = tid & 63;
    const int w    = tid >> 6;        // wave 0..7
    const int b0   = blockIdx.x * 4;  // batch row base

    // ---- stage x transposed (coalesced) ----
    {
        const float* xp = x + b0 * S_LEN;
        #pragma unroll
        for (int r = 0; r < 4; ++r) xr[r][tid] = xp[r * S_LEN + tid];
    }
    ((unsigned short*)hb)[tid] = 0;   // zero hb[0]

    const int jl = lane & 15;
    const int kg = lane >> 4;         // 0..3
    const int j  = w * 16 + jl;       // owned h-col

    // ---- Wh into registers as B-fragments (bf16) ----
    // B-frag lane l elem e: k = 32*kk + 8*(l>>4) + e, n = l&15
    const float* WhA[4] = { Wgh, Wih, Wfh, Woh };
    short8 bfrag[4][4];
    #pragma unroll
    for (int g = 0; g < 4; ++g) {
        #pragma unroll
        for (int kk = 0; kk < 4; ++kk) {
            const float* src = WhA[g] + (kk * 32 + kg * 8) * H_DIM + j;
            short8 v;
            #pragma unroll
            for (int e = 0; e < 8; ++e) v[e] = (short)f2bf(src[e * H_DIM]);
            bfrag[g][kk] = v;
        }
    }
    const float wxv[4] = { Wgx[j], Wix[j], Wfx[j], Wox[j] };
    const float bv[4]  = { bg[j],  bi[j],  bff[j], bo[j]  };

    // A-frag read: active lanes lane%4==0 (q=lane/4) read bytes q*16 + kk*256
    const bool aActive = (lane & 3) == 0;
    const int  abase   = (lane >> 2) * 16;
    // h-write (batch kg, col j): ushort idx in A-frag order
    const int  widx    = kg * 8 + ((j >> 3) & 3) * 32 + (j >> 5) * 128 + (j & 7);

    float cst  = 0.f;
    float hcur = 0.f;

    short8 afr[4];
    #pragma unroll
    for (int kk = 0; kk < 4; ++kk) afr[kk] = short8{0,0,0,0,0,0,0,0};

    __syncthreads();

    unsigned short* const h0 = &hb[0][0];
    unsigned short* const h1 = &hb[1][0];

    auto step = [&](const unsigned short* src, unsigned short* dst, float xv) {
        if (aActive) {
            const char* base = (const char*)src + abase;
            #pragma unroll
            for (int kk = 0; kk < 4; ++kk)
                afr[kk] = *(const short8*)(base + kk * 256);
        }
        // seeds go into the MFMA C operand (elem0 is the only one ever read;
        // elems 1..3 accumulate zero A-rows, splat keeps them finite)
        f32x4 a0[4], a1[4];
        #pragma unroll
        for (int g = 0; g < 4; ++g) {
            const float sd = __builtin_fmaf(xv, wxv[g], bv[g]);
            a0[g] = f32x4{ sd, sd, sd, sd };
            a1[g] = f32x4{ 0.f, 0.f, 0.f, 0.f };
        }
        #pragma unroll
        for (int g = 0; g < 4; ++g) {
            a0[g] = __builtin_amdgcn_mfma_f32_16x16x32_bf16(afr[0], bfrag[g][0], a0[g], 0, 0, 0);
            a1[g] = __builtin_amdgcn_mfma_f32_16x16x32_bf16(afr[2], bfrag[g][2], a1[g], 0, 0, 0);
        }
        #pragma unroll
        for (int g = 0; g < 4; ++g) {
            a0[g] = __builtin_amdgcn_mfma_f32_16x16x32_bf16(afr[1], bfrag[g][1], a0[g], 0, 0, 0);
            a1[g] = __builtin_amdgcn_mfma_f32_16x16x32_bf16(afr[3], bfrag[g][3], a1[g], 0, 0, 0);
        }

        __builtin_amdgcn_s_setprio(1);   // serial tail: finish fast, cut skew
        const float pg = a0[0][0] + a1[0][0];
        const float pi = a0[1][0] + a1[1][0];
        const float pf = a0[2][0] + a1[2][0];
        const float po = a0[3][0] + a1[3][0];
        const float tg = fast_tanh(pg);
        const float si = fast_sigmoid(pi);
        const float sf = fast_sigmoid(pf);
        const float so = fast_sigmoid(po);
        const float cn = __builtin_fmaf(cst, sf, tg * si);
        cst  = cn;
        const float hn = fast_tanh(cn) * so;
        hcur = hn;
        unsigned pk;
        asm("v_cvt_pk_bf16_f32 %0, %1, %2" : "=v"(pk) : "v"(hn), "v"(hn));
        dst[widx] = (unsigned short)pk;
        __builtin_amdgcn_s_setprio(0);
        __syncthreads();
    };

    f32x4 xq = *(const f32x4*)&xr[kg][0];
    for (int t4 = 0; t4 < S_LEN; t4 += 4) {
        step(h0, h1, xq[0]);
        // prefetch next x quad off the post-barrier burst window
        const int nt = (t4 + 4) & (S_LEN - 1);
        const f32x4 xnq = *(const f32x4*)&xr[kg][nt];
        step(h1, h0, xq[1]);
        step(h0, h1, xq[2]);
        step(h1, h0, xq[3]);
        xq = xnq;
    }

    // ---- epilogue: logits = h_last @ W_ph + b_p ----
    hfin[kg][j] = hcur;
    __syncthreads();

    if (tid < 4 * C_DIM) {
        const int b = tid / C_DIM, cc = tid % C_DIM;
        float s = bp[cc];
        #pragma unroll 8
        for (int k = 0; k < H_DIM; ++k) s += hfin[b][k] * Wph[k * C_DIM + cc];
        out[(b0 + b) * C_DIM + cc] = s;
    }
}

extern "C" void kernel_launch(void* const* d_in, const int* in_sizes, int n_in,
                              void* d_out, int out_size, void* d_ws, size_t ws_size,
                              hipStream_t stream) {
    const float* x   = (const float*)d_in[0];
    const float* Wgx = (const float*)d_in[1];
    const float* Wgh = (const float*)d_in[2];
    const float* Wix = (const float*)d_in[3];
    const float* Wih = (const float*)d_in[4];
    const float* Wfx = (const float*)d_in[5];
    const float* Wfh = (const float*)d_in[6];
    const float* Wox = (const float*)d_in[7];
    const float* Woh = (const float*)d_in[8];
    const float* Wph = (const float*)d_in[9];
    const float* bg  = (const float*)d_in[10];
    const float* bi  = (const float*)d_in[11];
    const float* bf  = (const float*)d_in[12];
    const float* bo  = (const float*)d_in[13];
    const float* bp  = (const float*)d_in[14];
    float* out = (float*)d_out;

    lstm_fused<<<dim3(256), dim3(512), 0, stream>>>(
        x, Wgx, Wgh, Wix, Wih, Wfx, Wfh, Wox, Woh, Wph,
        bg, bi, bf, bo, bp, out);
}

// Round 8
// 237.510 us; speedup vs baseline: 1.7345x; 1.0379x over previous
//
#include <hip/hip_runtime.h>

#define S_LEN 512
#define H_DIM 128
#define C_DIM 10

typedef __attribute__((ext_vector_type(8))) short short8;
typedef __attribute__((ext_vector_type(4))) float f32x4;

__device__ __forceinline__ unsigned short f2bf(float f) {
    union { float f; unsigned u; } v; v.f = f;
    return (unsigned short)((v.u + 0x7FFFu + ((v.u >> 16) & 1u)) >> 16);
}

__device__ __forceinline__ float fast_sigmoid(float x) {
    float e = __builtin_amdgcn_exp2f(-1.4426950408889634f * x);
    return __builtin_amdgcn_rcpf(1.0f + e);
}
__device__ __forceinline__ float fast_tanh(float x) {
    float e = __builtin_amdgcn_exp2f(2.8853900817779268f * x);  // e^{2x}
    return 1.0f - 2.0f * __builtin_amdgcn_rcpf(e + 1.0f);
}

// R8 = exact resubmission of R2 (best measured: 218us; every subsequent
// "improvement" regressed: R3 238, R4 294, R5 252, R6 412, R7 246).
// 256 blocks x 512 threads (8 waves). Block owns 4 batch rows at MFMA
// M-rows 4b; wave w owns gate-columns [16w,16w+16) of all 4 gates ->
// 16 MFMA/wave/step, 1 LSTM cell per lane. Wh in registers as bf16
// B-fragments. h through double-buffered LDS (A-read 272B-stride; bank
// conflicts measured irrelevant - off critical path). T_iter model:
// read 120 + MFMA pipe 640 + act 100 + write 30 + barrier 100 ~= 1030cy
// floor; this measures ~1150cy/step.
__global__ __launch_bounds__(512, 2) void lstm_fused(
    const float* __restrict__ x,
    const float* __restrict__ Wgx, const float* __restrict__ Wgh,
    const float* __restrict__ Wix, const float* __restrict__ Wih,
    const float* __restrict__ Wfx, const float* __restrict__ Wfh,
    const float* __restrict__ Wox, const float* __restrict__ Woh,
    const float* __restrict__ Wph,
    const float* __restrict__ bg, const float* __restrict__ bi,
    const float* __restrict__ bff, const float* __restrict__ bo,
    const float* __restrict__ bp,
    float* __restrict__ out)
{
    __shared__ float xr[4][516];                                      // pad: kg rows bank-shifted
    __shared__ __attribute__((aligned(16))) unsigned short hb[2][512]; // A-frag order, 1KB/buf
    __shared__ float hfin[4][H_DIM];

    const int tid  = threadIdx.x;
    const int lane = tid & 63;
    const int w    = tid >> 6;        // wave 0..7
    const int b0   = blockIdx.x * 4;  // batch row base

    // ---- stage x (coalesced global, conflict-free LDS writes) ----
    {
        const float* xp = x + b0 * S_LEN + tid;
        #pragma unroll
        for (int r = 0; r < 4; ++r) xr[r][tid] = xp[r * S_LEN];
    }
    ((unsigned short*)hb)[tid] = 0;   // zero hb[0] (512 ushorts)

    const int jl = lane & 15;   // col within 16-wide tile
    const int kg = lane >> 4;   // 0..3
    const int j  = w * 16 + jl; // h-column 0..127 owned by this lane

    // ---- Wh into registers as B-fragments: B[k][n=j], bf16 ----
    const float* WhA[4] = { Wgh, Wih, Wfh, Woh };
    short8 bfrag[4][4];
    #pragma unroll
    for (int g = 0; g < 4; ++g) {
        #pragma unroll
        for (int kk = 0; kk < 4; ++kk) {
            const float* src = WhA[g] + (kk * 32 + kg * 8) * H_DIM + j;
            short8 v;
            #pragma unroll
            for (int e = 0; e < 8; ++e) v[e] = (short)f2bf(src[e * H_DIM]);
            bfrag[g][kk] = v;
        }
    }
    const float wxv[4] = { Wgx[j], Wix[j], Wfx[j], Wox[j] };
    const float bv[4]  = { bg[j],  bi[j],  bff[j], bo[j]  };

    // A-frag read: lane 4q needs h[batch q&3][32kk + 8*(q>>2) + e]
    // layout offset = kk*256 + (q>>2)*64 + (q&3)*16 = kk*256 + q*16
    const bool aActive = (lane & 3) == 0;
    const int  abase   = (lane >> 2) * 16;          // + kk*256

    // h write: even-j lanes write dword {h[j], h[j+1]}
    // byte = (j>>5)*256 + ((j>>3)&3)*64 + kg*16 + (j&7)*2
    const bool wActive = (jl & 1) == 0;
    const int  wbyte   = (j >> 5) * 256 + ((j >> 3) & 3) * 64 + kg * 16 + (j & 7) * 2;

    float cst  = 0.f;
    float hcur = 0.f;

    short8 afr[4];
    #pragma unroll
    for (int kk = 0; kk < 4; ++kk) afr[kk] = short8{0,0,0,0,0,0,0,0};

    __syncthreads();

    auto step = [&](const unsigned short* src, unsigned short* dst, float xv) {
        if (aActive) {
            const char* base = (const char*)src + abase;
            #pragma unroll
            for (int kk = 0; kk < 4; ++kk)
                afr[kk] = *(const short8*)(base + kk * 256);
        }
        f32x4 a0[4] = {}, a1[4] = {};
        #pragma unroll
        for (int g = 0; g < 4; ++g) {
            a0[g] = __builtin_amdgcn_mfma_f32_16x16x32_bf16(afr[0], bfrag[g][0], a0[g], 0, 0, 0);
            a1[g] = __builtin_amdgcn_mfma_f32_16x16x32_bf16(afr[2], bfrag[g][2], a1[g], 0, 0, 0);
            a0[g] = __builtin_amdgcn_mfma_f32_16x16x32_bf16(afr[1], bfrag[g][1], a0[g], 0, 0, 0);
            a1[g] = __builtin_amdgcn_mfma_f32_16x16x32_bf16(afr[3], bfrag[g][3], a1[g], 0, 0, 0);
        }
        const float pg = a0[0][0] + a1[0][0] + xv * wxv[0] + bv[0];
        const float pi = a0[1][0] + a1[1][0] + xv * wxv[1] + bv[1];
        const float pf = a0[2][0] + a1[2][0] + xv * wxv[2] + bv[2];
        const float po = a0[3][0] + a1[3][0] + xv * wxv[3] + bv[3];
        const float cn = fast_tanh(pg) * fast_sigmoid(pi) + cst * fast_sigmoid(pf);
        cst  = cn;
        hcur = fast_tanh(cn) * fast_sigmoid(po);
        const float hnb = __shfl_xor(hcur, 1);  // neighbor column j^1
        if (wActive) {
            unsigned pk;
            asm("v_cvt_pk_bf16_f32 %0, %1, %2" : "=v"(pk) : "v"(hcur), "v"(hnb));
            *(unsigned*)((char*)dst + wbyte) = pk;
        }
        __syncthreads();
    };

    unsigned short* h0 = &hb[0][0];
    unsigned short* h1 = &hb[1][0];
    for (int t = 0; t < S_LEN; t += 4) {
        const f32x4 xq = *(const f32x4*)&xr[kg][t];
        step(h0, h1, xq[0]);
        step(h1, h0, xq[1]);
        step(h0, h1, xq[2]);
        step(h1, h0, xq[3]);
    }

    // ---- epilogue: logits = h_last @ W_ph + b_p ----
    hfin[kg][j] = hcur;
    __syncthreads();

    if (tid < 4 * C_DIM) {
        const int b = tid / C_DIM, cc = tid % C_DIM;
        float s = bp[cc];
        #pragma unroll 4
        for (int k = 0; k < H_DIM; ++k) s += hfin[b][k] * Wph[k * C_DIM + cc];
        out[(b0 + b) * C_DIM + cc] = s;
    }
}

extern "C" void kernel_launch(void* const* d_in, const int* in_sizes, int n_in,
                              void* d_out, int out_size, void* d_ws, size_t ws_size,
                              hipStream_t stream) {
    const float* x   = (const float*)d_in[0];
    const float* Wgx = (const float*)d_in[1];
    const float* Wgh = (const float*)d_in[2];
    const float* Wix = (const float*)d_in[3];
    const float* Wih = (const float*)d_in[4];
    const float* Wfx = (const float*)d_in[5];
    const float* Wfh = (const float*)d_in[6];
    const float* Wox = (const float*)d_in[7];
    const float* Woh = (const float*)d_in[8];
    const float* Wph = (const float*)d_in[9];
    const float* bg  = (const float*)d_in[10];
    const float* bi  = (const float*)d_in[11];
    const float* bf  = (const float*)d_in[12];
    const float* bo  = (const float*)d_in[13];
    const float* bp  = (const float*)d_in[14];
    float* out = (float*)d_out;

    lstm_fused<<<dim3(256), dim3(512), 0, stream>>>(
        x, Wgx, Wgh, Wix, Wih, Wfx, Wfh, Wox, Woh, Wph,
        bg, bi, bf, bo, bp, out);
}

// Round 9
// 217.904 us; speedup vs baseline: 1.8906x; 1.0900x over previous
//
#include <hip/hip_runtime.h>

#define S_LEN 512
#define H_DIM 128
#define C_DIM 10

typedef __attribute__((ext_vector_type(8))) short short8;
typedef __attribute__((ext_vector_type(4))) float f32x4;

__device__ __forceinline__ unsigned short f2bf(float f) {
    union { float f; unsigned u; } v; v.f = f;
    return (unsigned short)((v.u + 0x7FFFu + ((v.u >> 16) & 1u)) >> 16);
}

__device__ __forceinline__ float fast_sigmoid(float x) {
    float e = __builtin_amdgcn_exp2f(-1.4426950408889634f * x);
    return __builtin_amdgcn_rcpf(1.0f + e);
}
__device__ __forceinline__ float fast_tanh(float x) {
    float e = __builtin_amdgcn_exp2f(2.8853900817779268f * x);  // e^{2x}
    return 1.0f - 2.0f * __builtin_amdgcn_rcpf(e + 1.0f);
}

// R9 = byte-exact resubmission of the TRUE R2 artifact (218.03 us measured).
// (R8 was mistakenly rebuilt from R3's layout: A-frag order + shfl pack-write
// -> 237.5 us, matching R3's 237.6. The shfl_xor on the serial chain before
// the barrier is the regression; this artifact has a plain per-lane
// ds_write_b16 and depth-4 gate-interleaved MFMA chains.)
// 256 blocks x 512 threads (8 waves, 2/SIMD). Block owns 4 batch rows at
// MFMA M-rows 4b; wave w owns gate-columns [16w,16w+16) of all 4 gates ->
// 16 MFMA/wave/step, 1 LSTM cell per lane. Wh in registers as bf16
// B-fragments. h through double-buffered LDS hb[2][4][136].
__global__ __launch_bounds__(512, 2) void lstm_fused(
    const float* __restrict__ x,
    const float* __restrict__ Wgx, const float* __restrict__ Wgh,
    const float* __restrict__ Wix, const float* __restrict__ Wih,
    const float* __restrict__ Wfx, const float* __restrict__ Wfh,
    const float* __restrict__ Wox, const float* __restrict__ Woh,
    const float* __restrict__ Wph,
    const float* __restrict__ bg, const float* __restrict__ bi,
    const float* __restrict__ bff, const float* __restrict__ bo,
    const float* __restrict__ bp,
    float* __restrict__ out)
{
    __shared__ float xT[S_LEN][5];                                  // pad-5: conflict-free
    __shared__ __attribute__((aligned(16))) unsigned short hb[2][4][136]; // bf16 h, row pad 16B
    __shared__ float hfin[4][H_DIM];

    const int tid  = threadIdx.x;
    const int lane = tid & 63;
    const int w    = tid >> 6;        // wave 0..7
    const int b0   = blockIdx.x * 4;  // batch row base

    // ---- stage x transposed: xT[t][r] = x[b0+r][t] (coalesced reads) ----
    {
        const float* xp = x + b0 * S_LEN + tid;
        #pragma unroll
        for (int r = 0; r < 4; ++r) xT[tid][r] = xp[r * S_LEN];
    }
    // zero h buffer 0
    {
        unsigned short* hz = &hb[0][0][0];
        for (int i2 = tid; i2 < 4 * 136; i2 += 512) hz[i2] = 0;
    }

    const int jl = lane & 15;   // col within 16-wide tile
    const int kg = lane >> 4;   // 0..3
    const int j  = w * 16 + jl; // h-column 0..127 owned by this lane

    // ---- Wh into registers as B-fragments: B[k][n=j], bf16 ----
    // B-frag lane l elem e: k = 32*kk + 8*(l>>4) + e, n = l&15
    const float* WhA[4] = { Wgh, Wih, Wfh, Woh };
    short8 bfrag[4][4];
    #pragma unroll
    for (int g = 0; g < 4; ++g) {
        #pragma unroll
        for (int kk = 0; kk < 4; ++kk) {
            const float* src = WhA[g] + (kk * 32 + kg * 8) * H_DIM + j;
            short8 v;
            #pragma unroll
            for (int e = 0; e < 8; ++e) v[e] = (short)f2bf(src[e * H_DIM]);
            bfrag[g][kk] = v;
        }
    }
    const float wxv[4] = { Wgx[j], Wix[j], Wfx[j], Wox[j] };
    const float bv[4]  = { bg[j],  bi[j],  bff[j], bo[j]  };

    // A-frag source: active lanes (lane&3)==0 read batch row (lane&15)>>2
    // at k-chunk = 32*kk + 8*(lane>>4). Byte offset inside one hb buffer:
    const bool aActive = (lane & 3) == 0;
    const int  abase   = ((lane & 15) >> 2) * 272 + (lane >> 4) * 16; // +kk*64

    float cst  = 0.f;   // cell state for (batch kg, col j)
    float hcur = 0.f;

    short8 afr[4];
    #pragma unroll
    for (int kk = 0; kk < 4; ++kk) afr[kk] = short8{0,0,0,0,0,0,0,0};

    __syncthreads();

    auto step = [&](int t, const unsigned short* src, unsigned short* dst) {
        if (aActive) {
            const char* base = (const char*)src + abase;
            #pragma unroll
            for (int kk = 0; kk < 4; ++kk)
                afr[kk] = *(const short8*)(base + kk * 64);
        }
        f32x4 acc[4] = {};
        #pragma unroll
        for (int kk = 0; kk < 4; ++kk) {
            #pragma unroll
            for (int g = 0; g < 4; ++g)
                acc[g] = __builtin_amdgcn_mfma_f32_16x16x32_bf16(
                             afr[kk], bfrag[g][kk], acc[g], 0, 0, 0);
        }
        const float xv = xT[t][kg];
        const float pg = acc[0][0] + xv * wxv[0] + bv[0];
        const float pi = acc[1][0] + xv * wxv[1] + bv[1];
        const float pf = acc[2][0] + xv * wxv[2] + bv[2];
        const float po = acc[3][0] + xv * wxv[3] + bv[3];
        const float cn = fast_tanh(pg) * fast_sigmoid(pi) + cst * fast_sigmoid(pf);
        cst = cn;
        hcur = fast_tanh(cn) * fast_sigmoid(po);
        *((unsigned short*)dst + kg * 136 + j) = f2bf(hcur);
        __syncthreads();
    };

    for (int t = 0; t < S_LEN; t += 2) {
        step(t,     &hb[0][0][0], &hb[1][0][0]);
        step(t + 1, &hb[1][0][0], &hb[0][0][0]);
    }

    // ---- epilogue: logits = h_last @ W_ph + b_p ----
    hfin[kg][j] = hcur;
    __syncthreads();

    if (tid < 4 * C_DIM) {
        const int b = tid / C_DIM, cc = tid % C_DIM;
        float s = bp[cc];
        #pragma unroll 4
        for (int k = 0; k < H_DIM; ++k) s += hfin[b][k] * Wph[k * C_DIM + cc];
        out[(b0 + b) * C_DIM + cc] = s;
    }
}

extern "C" void kernel_launch(void* const* d_in, const int* in_sizes, int n_in,
                              void* d_out, int out_size, void* d_ws, size_t ws_size,
                              hipStream_t stream) {
    const float* x   = (const float*)d_in[0];
    const float* Wgx = (const float*)d_in[1];
    const float* Wgh = (const float*)d_in[2];
    const float* Wix = (const float*)d_in[3];
    const float* Wih = (const float*)d_in[4];
    const float* Wfx = (const float*)d_in[5];
    const float* Wfh = (const float*)d_in[6];
    const float* Wox = (const float*)d_in[7];
    const float* Woh = (const float*)d_in[8];
    const float* Wph = (const float*)d_in[9];
    const float* bg  = (const float*)d_in[10];
    const float* bi  = (const float*)d_in[11];
    const float* bf  = (const float*)d_in[12];
    const float* bo  = (const float*)d_in[13];
    const float* bp  = (const float*)d_in[14];
    float* out = (float*)d_out;

    lstm_fused<<<dim3(256), dim3(512), 0, stream>>>(
        x, Wgx, Wgh, Wix, Wih, Wfx, Wfh, Wox, Woh, Wph,
        bg, bi, bf, bo, bp, out);
}